// Round 5
// baseline (482.026 us; speedup 1.0000x reference)
//
#include <hip/hip_runtime.h>

#define D        128
#define KCODES   2048
#define NROWS    32768
#define BATCH    8192

typedef _Float16 f16x8  __attribute__((ext_vector_type(8)));
typedef float    f32x16 __attribute__((ext_vector_type(16)));

#define MFMA(a, b, c) __builtin_amdgcn_mfma_f32_32x32x16_f16((a), (b), (c), 0, 0, 0)
#define INV2048 4.8828125e-4f

static __device__ __forceinline__ f32x16 zero16() {
    f32x16 z;
#pragma unroll
    for (int i = 0; i < 16; ++i) z[i] = 0.0f;
    return z;
}

static __device__ __forceinline__ void gload16(const void* g, void* l) {
    __builtin_amdgcn_global_load_lds(
        (const __attribute__((address_space(1))) unsigned int*)g,
        (__attribute__((address_space(3))) unsigned int*)l, 16, 0, 0);
}

// ---------------------------------------------------------------------------
// Kernel A: W -> (wh, wl) fp16 hi/lo, fragment-linear layout + fp32 ||W||^2.
// Lane mapping (verified R2-R4): for 32-code block n0, kstep ks, lane l holds
// W[n0*32 + (l&31)][ks*16 + (l>>5)*8 + j], stored at f16x8 idx ((n0*8+ks)*64+l).
// ---------------------------------------------------------------------------
__global__ void wconv_kernel(const float* __restrict__ W,
                             _Float16* __restrict__ whf, _Float16* __restrict__ wlf,
                             float* __restrict__ wnorm) {
    int gid = blockIdx.x * 256 + threadIdx.x;    // 32768 = 2048 codes x 16 slots
    int n = gid >> 4, s = gid & 15;
    const float4* src = (const float4*)(W + (size_t)n * D + s * 8);
    float4 a = src[0], b = src[1];
    float va[8] = {a.x, a.y, a.z, a.w, b.x, b.y, b.z, b.w};
    f16x8 hi, lo;
    float ss = 0.0f;
#pragma unroll
    for (int j = 0; j < 8; ++j) {
        _Float16 h = (_Float16)va[j];
        hi[j] = h;
        lo[j] = (_Float16)((va[j] - (float)h) * 2048.0f);
        ss += va[j] * va[j];
    }
    int ks = s >> 1, sub = s & 1;
    size_t idx = ((size_t)((n >> 5) * 8 + ks) * 64 + sub * 32 + (n & 31));
    ((f16x8*)whf)[idx] = hi;
    ((f16x8*)wlf)[idx] = lo;
#pragma unroll
    for (int m = 1; m <= 8; m <<= 1) ss += __shfl_xor(ss, m);
    if (s == 0) wnorm[n] = ss;
}

// ---------------------------------------------------------------------------
// Kernel B: fused MFMA scores + argmin, counted-vmcnt ring pipeline.
// Grid 256 = 128 row-blocks x 2 code-halves (XCD-partitioned).
// Block 512 thr = 8 waves = 4 wm (64 rows) x 2 wn (32 codes/chunk each).
// 16 chunks of 64 codes; 4 x 32KB LDS ring, 3 chunks prefetched ahead.
// Per chunk: vmcnt(8) -> raw barrier -> STAGE(t+3) -> 24 ds_read_b128 +
// 48 MFMA (setprio-wrapped) -> packed-meta argmin fold (t in low 4 bits).
// ---------------------------------------------------------------------------
extern "C" __global__ void __launch_bounds__(512)
__attribute__((amdgpu_flat_work_group_size(512, 512)))
__attribute__((amdgpu_waves_per_eu(2, 2)))
vq_argmin(const float* __restrict__ f,
          const _Float16* __restrict__ whf, const _Float16* __restrict__ wlf,
          const float* __restrict__ wnorm,
          float* __restrict__ bsp, int* __restrict__ bcp) {
    extern __shared__ unsigned char lds[];   // 4 x 32768 ring; epilogue reuses

    const int b   = blockIdx.x;
    const int cH  = (b & 7) >> 2;            // code half 0/1 -> XCD group
    const int rb  = (b >> 3) * 4 + (b & 3);  // row block 0..127
    const int tid = threadIdx.x;
    const int w   = tid >> 6, l = tid & 63;
    const int wm  = w >> 1, wn = w & 1;
    const int l31 = l & 31, lh = l >> 5;
    const int rowsBase = rb * 256 + wm * 64;

    // ---- wnorm preload (16 regs; issued first so they drain earliest) ----
    float wnv[16];
#pragma unroll
    for (int t = 0; t < 16; ++t)
        wnv[t] = wnorm[cH * 1024 + t * 64 + wn * 32 + l31];

    // ---- A-fragments: 64 rows of f in hi/lo fp16 (128 VGPR); the per-lane
    //      conversions consume every f load, draining vmcnt before staging ----
    f16x8 fh[2][8], fl[2][8];
#pragma unroll
    for (int mf = 0; mf < 2; ++mf) {
#pragma unroll
        for (int ks = 0; ks < 8; ++ks) {
            const float4* p = (const float4*)(f + (size_t)(rowsBase + mf * 32 + l31) * D
                                              + ks * 16 + lh * 8);
            float4 a = p[0], bb = p[1];
            float va[8] = {a.x, a.y, a.z, a.w, bb.x, bb.y, bb.z, bb.w};
            f16x8 hi, lo;
#pragma unroll
            for (int j = 0; j < 8; ++j) {
                _Float16 h = (_Float16)va[j];
                hi[j] = h;
                lo[j] = (_Float16)((va[j] - (float)h) * 2048.0f);
            }
            fh[mf][ks] = hi;
            fl[mf][ks] = lo;
        }
    }

    const char* ghB = (const char*)whf + (size_t)cH * 262144;   // cH*32*8192
    const char* glB = (const char*)wlf + (size_t)cH * 262144;

#define STAGE(c) {                                                          \
        unsigned char* dB = lds + ((c) & 3) * 32768;                        \
        const char* gh = ghB + (size_t)(c) * 16384;                         \
        const char* gl = glB + (size_t)(c) * 16384;                         \
        gload16(gh + tid * 16,        dB + tid * 16);                       \
        gload16(gh + 8192 + tid * 16, dB + 8192 + tid * 16);                \
        gload16(gl + tid * 16,        dB + 16384 + tid * 16);               \
        gload16(gl + 8192 + tid * 16, dB + 24576 + tid * 16);               \
    }

    // ---- prologue: 3 chunks in flight ----
    STAGE(0); STAGE(1); STAGE(2);

    float bestP[32];
#pragma unroll
    for (int e = 0; e < 32; ++e) bestP[e] = 3.4e38f;

#pragma unroll
    for (int t = 0; t < 16; ++t) {
        // wait for chunk t's staging (t+1, t+2 stay in flight = 8 loads)
        if (t <= 13)      asm volatile("s_waitcnt vmcnt(8)" ::: "memory");
        else if (t == 14) asm volatile("s_waitcnt vmcnt(4)" ::: "memory");
        else              asm volatile("s_waitcnt vmcnt(0)" ::: "memory");
        __builtin_amdgcn_s_barrier();            // raw: no implicit drain
        asm volatile("" ::: "memory");           // compile-time fence

        if (t + 3 < 16) STAGE(t + 3);            // overwrites buf of chunk t-1

        const unsigned char* wb = lds + (t & 3) * 32768 + wn * 8192;
        f32x16 a0 = zero16(), a1 = zero16();

        __builtin_amdgcn_s_setprio(1);
        // cross terms (scaled by 2048)
#pragma unroll
        for (int ks = 0; ks < 8; ++ks) {
            f16x8 wh = *(const f16x8*)(wb + ks * 1024 + l * 16);
            f16x8 wl = *(const f16x8*)(wb + 16384 + ks * 1024 + l * 16);
            a0 = MFMA(fh[0][ks], wl, a0);
            a0 = MFMA(fl[0][ks], wh, a0);
            a1 = MFMA(fh[1][ks], wl, a1);
            a1 = MFMA(fl[1][ks], wh, a1);
        }
#pragma unroll
        for (int r = 0; r < 16; ++r) { a0[r] *= INV2048; a1[r] *= INV2048; }
        // hi*hi accumulated on top (C-input carries scaled partial)
#pragma unroll
        for (int ks = 0; ks < 8; ++ks) {
            f16x8 wh = *(const f16x8*)(wb + ks * 1024 + l * 16);
            a0 = MFMA(fh[0][ks], wh, a0);
            a1 = MFMA(fh[1][ks], wh, a1);
        }
        __builtin_amdgcn_s_setprio(0);

        // ---- fold: pack t into low 4 mantissa bits, single v_min_f32 ----
        const float wv = wnv[t];
#pragma unroll
        for (int r = 0; r < 16; ++r) {
            float s0 = fmaf(-2.0f, a0[r], wv);
            unsigned p0 = (__float_as_uint(s0) & 0xFFFFFFF0u) | (unsigned)t;
            bestP[r] = fminf(bestP[r], __uint_as_float(p0));
            float s1 = fmaf(-2.0f, a1[r], wv);
            unsigned p1 = (__float_as_uint(s1) & 0xFFFFFFF0u) | (unsigned)t;
            bestP[16 + r] = fminf(bestP[16 + r], __uint_as_float(p1));
        }
    }
#undef STAGE

    // ---- reduction: butterfly over 32 code-cols, then across wn pair ----
    __syncthreads();                             // full drain; LDS reuse below
    float* redS = (float*)lds;                   // [256][2]
    int*   redC = (int*)(lds + 2048);            // [256][2]
#pragma unroll
    for (int e = 0; e < 32; ++e) {
        float s = bestP[e];
        int tE = (int)(__float_as_uint(s) & 15u);
        int c  = cH * 1024 + tE * 64 + wn * 32 + l31;
#pragma unroll
        for (int msk = 1; msk <= 16; msk <<= 1) {
            float s2 = __shfl_xor(s, msk);
            int   c2 = __shfl_xor(c, msk);
            if (s2 < s || (s2 == s && c2 < c)) { s = s2; c = c2; }
        }
        if (l31 == 0) {
            int mf = e >> 4, r = e & 15;
            int row = wm * 64 + mf * 32 + (r & 3) + 8 * (r >> 2) + 4 * lh;
            redS[row * 2 + wn] = s;
            redC[row * 2 + wn] = c;
        }
    }
    __syncthreads();
    if (tid < 256) {
        float s0 = redS[tid * 2], s1 = redS[tid * 2 + 1];
        int   c0 = redC[tid * 2], c1 = redC[tid * 2 + 1];
        bool take1 = (s1 < s0) || (s1 == s0 && c1 < c0);
        bsp[(size_t)cH * NROWS + rb * 256 + tid] = take1 ? s1 : s0;
        bcp[(size_t)cH * NROWS + rb * 256 + tid] = take1 ? c1 : c0;
    }
}

// ---------------------------------------------------------------------------
// Kernel C: merge the two code-half partials, gather W[j], write out + loss.
// ---------------------------------------------------------------------------
__global__ void gather_kernel(const float* __restrict__ f, const float* __restrict__ W,
                              const float* __restrict__ bsp, const int* __restrict__ bcp,
                              float* __restrict__ loss, float* __restrict__ outv) {
    int b  = blockIdx.x;
    int wv = threadIdx.x >> 6;
    int l  = threadIdx.x & 63;
    int n  = b * 4 + wv;
    float s0 = bsp[n], s1 = bsp[NROWS + n];
    int   c0 = bcp[n], c1 = bcp[NROWS + n];
    int j = (s1 < s0) ? c1 : c0;   // tie -> c0 (always < c1)
    float2 fv = reinterpret_cast<const float2*>(f + (size_t)n * D)[l];
    float2 wj = reinterpret_cast<const float2*>(W + (size_t)j * D)[l];
    reinterpret_cast<float2*>(outv + (size_t)n * D)[l] = wj;
    float dx = fv.x - wj.x, dy = fv.y - wj.y;
    float s = dx * dx + dy * dy;
#pragma unroll
    for (int off = 32; off; off >>= 1) s += __shfl_down(s, off);
    __shared__ float ls[4];
    if (l == 0) ls[wv] = s;
    __syncthreads();
    if (threadIdx.x == 0)
        loss[b] = 1.25f * 0.25f * (ls[0] + ls[1] + ls[2] + ls[3]);
}

// ---------------------------------------------------------------------------
extern "C" void kernel_launch(void* const* d_in, const int* in_sizes, int n_in,
                              void* d_out, int out_size, void* d_ws, size_t ws_size,
                              hipStream_t stream) {
    const float* f = (const float*)d_in[0];   // [8192,512] -> 32768 rows of 128
    const float* W = (const float*)d_in[1];   // [2048,128]

    float* loss = (float*)d_out;              // [8192]
    float* outv = (float*)d_out + BATCH;      // [8192*512]

    // workspace layout
    float*    wnorm = (float*)d_ws;                              // @0       (8 KB)
    _Float16* whf   = (_Float16*)((char*)d_ws + 8192);           // @8K    (512 KB)
    _Float16* wlf   = (_Float16*)((char*)d_ws + 532480);         // @520K  (512 KB)
    float*    bsp   = (float*)((char*)d_ws + 1056768);           // @1032K (256 KB)
    int*      bcp   = (int*)((char*)d_ws + 1318912);             // @1288K (256 KB)

    wconv_kernel<<<KCODES * 16 / 256, 256, 0, stream>>>(W, whf, wlf, wnorm);

    hipLaunchKernelGGL(vq_argmin, dim3(256), dim3(512), 131072, stream,
                       f, whf, wlf, wnorm, bsp, bcp);

    gather_kernel<<<BATCH, 256, 0, stream>>>(f, W, bsp, bcp, loss, outv);
}

// Round 6
// 88.951 us; speedup vs baseline: 5.4190x; 5.4190x over previous
//
#include <hip/hip_runtime.h>

#define D        128
#define KCODES   2048
#define NROWS    32768
#define BATCH    8192

typedef _Float16 f16x8  __attribute__((ext_vector_type(8)));
typedef float    f32x16 __attribute__((ext_vector_type(16)));

#define MFMA(a, b, c) __builtin_amdgcn_mfma_f32_32x32x16_f16((a), (b), (c), 0, 0, 0)
#define INV2048 4.8828125e-4f

static __device__ __forceinline__ f32x16 zero16() {
    f32x16 z;
#pragma unroll
    for (int i = 0; i < 16; ++i) z[i] = 0.0f;
    return z;
}

static __device__ __forceinline__ void gload16(const void* g, void* l) {
    __builtin_amdgcn_global_load_lds(
        (const __attribute__((address_space(1))) unsigned int*)g,
        (__attribute__((address_space(3))) unsigned int*)l, 16, 0, 0);
}

// ---------------------------------------------------------------------------
// Kernel A: W -> (wh, wl) fp16 hi/lo, fragment-linear layout + fp32 ||W||^2.
// Lane mapping (verified R2-R5): for 32-code block n0, kstep ks, lane l holds
// W[n0*32 + (l&31)][ks*16 + (l>>5)*8 + j], stored at f16x8 idx ((n0*8+ks)*64+l).
// ---------------------------------------------------------------------------
__global__ void wconv_kernel(const float* __restrict__ W,
                             _Float16* __restrict__ whf, _Float16* __restrict__ wlf,
                             float* __restrict__ wnorm) {
    int gid = blockIdx.x * 256 + threadIdx.x;    // 32768 = 2048 codes x 16 slots
    int n = gid >> 4, s = gid & 15;
    const float4* src = (const float4*)(W + (size_t)n * D + s * 8);
    float4 a = src[0], b = src[1];
    float va[8] = {a.x, a.y, a.z, a.w, b.x, b.y, b.z, b.w};
    f16x8 hi, lo;
    float ss = 0.0f;
#pragma unroll
    for (int j = 0; j < 8; ++j) {
        _Float16 h = (_Float16)va[j];
        hi[j] = h;
        lo[j] = (_Float16)((va[j] - (float)h) * 2048.0f);
        ss += va[j] * va[j];
    }
    int ks = s >> 1, sub = s & 1;
    size_t idx = ((size_t)((n >> 5) * 8 + ks) * 64 + sub * 32 + (n & 31));
    ((f16x8*)whf)[idx] = hi;
    ((f16x8*)wlf)[idx] = lo;
#pragma unroll
    for (int m = 1; m <= 8; m <<= 1) ss += __shfl_xor(ss, m);
    if (s == 0) wnorm[n] = ss;
}

// ---------------------------------------------------------------------------
// Kernel B: fused MFMA scores + argmin, counted-vmcnt ring pipeline
// (register-safe: ROLLED main loop + peeled tail, wnorm in LDS).
// Grid 256 = 128 row-blocks x 2 code-halves (XCD-partitioned).
// Block 512 thr = 8 waves = 4 wm (64 rows) x 2 wn (32 codes/chunk each).
// 16 chunks of 64 codes; 4 x 32KB LDS ring + 4KB wnorm, 3 chunks ahead.
// Per chunk: vmcnt(8) -> raw s_barrier -> STAGE(t+3) -> 24 ds_read_b128 +
// 48 MFMA (setprio-wrapped) -> packed-t argmin fold.
// ---------------------------------------------------------------------------
extern "C" __global__ void __launch_bounds__(512)
__attribute__((amdgpu_flat_work_group_size(512, 512)))
__attribute__((amdgpu_waves_per_eu(2, 2)))
vq_argmin(const float* __restrict__ f,
          const _Float16* __restrict__ whf, const _Float16* __restrict__ wlf,
          const float* __restrict__ wnorm,
          float* __restrict__ bsp, int* __restrict__ bcp) {
    extern __shared__ unsigned char lds[];   // [4][32768] ring | wnorm @131072

    const int b   = blockIdx.x;
    const int cH  = (b & 7) >> 2;            // code half 0/1 -> XCD group
    const int rb  = (b >> 3) * 4 + (b & 3);  // row block 0..127
    const int tid = threadIdx.x;
    const int w   = tid >> 6, l = tid & 63;
    const int wm  = w >> 1, wn = w & 1;
    const int l31 = l & 31, lh = l >> 5;
    const int rowsBase = rb * 256 + wm * 64;

    // ---- stage this half's wnorm (1024 floats = 4KB) into LDS ----
    if (w < 4)
        gload16((const char*)wnorm + cH * 4096 + tid * 16, lds + 131072 + tid * 16);

    // ---- A-fragments: 64 rows of f in hi/lo fp16 (128 VGPR) ----
    f16x8 fh[2][8], fl[2][8];
#pragma unroll
    for (int mf = 0; mf < 2; ++mf) {
#pragma unroll
        for (int ks = 0; ks < 8; ++ks) {
            const float4* p = (const float4*)(f + (size_t)(rowsBase + mf * 32 + l31) * D
                                              + ks * 16 + lh * 8);
            float4 a = p[0], bb = p[1];
            float va[8] = {a.x, a.y, a.z, a.w, bb.x, bb.y, bb.z, bb.w};
            f16x8 hi, lo;
#pragma unroll
            for (int j = 0; j < 8; ++j) {
                _Float16 h = (_Float16)va[j];
                hi[j] = h;
                lo[j] = (_Float16)((va[j] - (float)h) * 2048.0f);
            }
            fh[mf][ks] = hi;
            fl[mf][ks] = lo;
        }
    }

    __syncthreads();    // full drain: wnorm LDS visible; vmcnt==0 for all waves

    const char* ghB = (const char*)whf + (size_t)cH * 262144;
    const char* glB = (const char*)wlf + (size_t)cH * 262144;

#define STAGE(c) {                                                          \
        unsigned char* dB = lds + ((c) & 3) * 32768;                        \
        const char* gh = ghB + (size_t)(c) * 16384;                         \
        const char* gl = glB + (size_t)(c) * 16384;                         \
        gload16(gh + tid * 16,        dB + tid * 16);                       \
        gload16(gh + 8192 + tid * 16, dB + 8192 + tid * 16);                \
        gload16(gl + tid * 16,        dB + 16384 + tid * 16);               \
        gload16(gl + 8192 + tid * 16, dB + 24576 + tid * 16);               \
    }

    STAGE(0); STAGE(1); STAGE(2);            // 12 loads in flight

    float bestP[32];
#pragma unroll
    for (int e = 0; e < 32; ++e) bestP[e] = 3.4e38f;

    const float* wnL = (const float*)(lds + 131072);

    // chunk body (inlined; t is runtime -> all reg indices compile-time)
    auto body = [&](int t) {
        const unsigned char* wb = lds + (t & 3) * 32768 + wn * 8192;
        f32x16 a0 = zero16(), a1 = zero16();
        __builtin_amdgcn_s_setprio(1);
#pragma unroll
        for (int ks = 0; ks < 8; ++ks) {
            f16x8 wh = *(const f16x8*)(wb + ks * 1024 + l * 16);
            f16x8 wl = *(const f16x8*)(wb + 16384 + ks * 1024 + l * 16);
            a0 = MFMA(fh[0][ks], wl, a0);
            a0 = MFMA(fl[0][ks], wh, a0);
            a1 = MFMA(fh[1][ks], wl, a1);
            a1 = MFMA(fl[1][ks], wh, a1);
        }
#pragma unroll
        for (int r = 0; r < 16; ++r) { a0[r] *= INV2048; a1[r] *= INV2048; }
#pragma unroll
        for (int ks = 0; ks < 8; ++ks) {
            f16x8 wh = *(const f16x8*)(wb + ks * 1024 + l * 16);
            a0 = MFMA(fh[0][ks], wh, a0);
            a1 = MFMA(fh[1][ks], wh, a1);
        }
        __builtin_amdgcn_s_setprio(0);
        const float wv = wnL[t * 64 + wn * 32 + l31];
#pragma unroll
        for (int r = 0; r < 16; ++r) {
            float s0 = fmaf(-2.0f, a0[r], wv);
            unsigned p0 = (__float_as_uint(s0) & 0xFFFFFFF0u) | (unsigned)t;
            bestP[r] = fminf(bestP[r], __uint_as_float(p0));
            float s1 = fmaf(-2.0f, a1[r], wv);
            unsigned p1 = (__float_as_uint(s1) & 0xFFFFFFF0u) | (unsigned)t;
            bestP[16 + r] = fminf(bestP[16 + r], __uint_as_float(p1));
        }
    };

#pragma unroll 1
    for (int t = 0; t < 13; ++t) {
        asm volatile("s_waitcnt vmcnt(8)" ::: "memory");
        __builtin_amdgcn_s_barrier();
        asm volatile("" ::: "memory");
        STAGE(t + 3);
        body(t);
    }
    asm volatile("s_waitcnt vmcnt(8)" ::: "memory");
    __builtin_amdgcn_s_barrier();
    asm volatile("" ::: "memory");
    body(13);
    asm volatile("s_waitcnt vmcnt(4)" ::: "memory");
    __builtin_amdgcn_s_barrier();
    asm volatile("" ::: "memory");
    body(14);
    asm volatile("s_waitcnt vmcnt(0)" ::: "memory");
    __builtin_amdgcn_s_barrier();
    asm volatile("" ::: "memory");
    body(15);
#undef STAGE

    // ---- reduction: butterfly over 32 code-cols, then across wn pair ----
    __syncthreads();
    float* redS = (float*)lds;                   // [256][2]
    int*   redC = (int*)(lds + 2048);            // [256][2]
#pragma unroll
    for (int e = 0; e < 32; ++e) {
        float s = bestP[e];
        int tE = (int)(__float_as_uint(s) & 15u);
        int c  = cH * 1024 + tE * 64 + wn * 32 + l31;
#pragma unroll
        for (int msk = 1; msk <= 16; msk <<= 1) {
            float s2 = __shfl_xor(s, msk);
            int   c2 = __shfl_xor(c, msk);
            if (s2 < s || (s2 == s && c2 < c)) { s = s2; c = c2; }
        }
        if (l31 == 0) {
            int mf = e >> 4, r = e & 15;
            int row = wm * 64 + mf * 32 + (r & 3) + 8 * (r >> 2) + 4 * lh;
            redS[row * 2 + wn] = s;
            redC[row * 2 + wn] = c;
        }
    }
    __syncthreads();
    if (tid < 256) {
        float s0 = redS[tid * 2], s1 = redS[tid * 2 + 1];
        int   c0 = redC[tid * 2], c1 = redC[tid * 2 + 1];
        bool take1 = (s1 < s0) || (s1 == s0 && c1 < c0);
        bsp[(size_t)cH * NROWS + rb * 256 + tid] = take1 ? s1 : s0;
        bcp[(size_t)cH * NROWS + rb * 256 + tid] = take1 ? c1 : c0;
    }
}

// ---------------------------------------------------------------------------
// Kernel C: merge the two code-half partials, gather W[j], write out + loss.
// ---------------------------------------------------------------------------
__global__ void gather_kernel(const float* __restrict__ f, const float* __restrict__ W,
                              const float* __restrict__ bsp, const int* __restrict__ bcp,
                              float* __restrict__ loss, float* __restrict__ outv) {
    int b  = blockIdx.x;
    int wv = threadIdx.x >> 6;
    int l  = threadIdx.x & 63;
    int n  = b * 4 + wv;
    float s0 = bsp[n], s1 = bsp[NROWS + n];
    int   c0 = bcp[n], c1 = bcp[NROWS + n];
    int j = (s1 < s0) ? c1 : c0;   // tie -> c0 (always < c1)
    float2 fv = reinterpret_cast<const float2*>(f + (size_t)n * D)[l];
    float2 wj = reinterpret_cast<const float2*>(W + (size_t)j * D)[l];
    reinterpret_cast<float2*>(outv + (size_t)n * D)[l] = wj;
    float dx = fv.x - wj.x, dy = fv.y - wj.y;
    float s = dx * dx + dy * dy;
#pragma unroll
    for (int off = 32; off; off >>= 1) s += __shfl_down(s, off);
    __shared__ float ls[4];
    if (l == 0) ls[wv] = s;
    __syncthreads();
    if (threadIdx.x == 0)
        loss[b] = 1.25f * 0.25f * (ls[0] + ls[1] + ls[2] + ls[3]);
}

// ---------------------------------------------------------------------------
extern "C" void kernel_launch(void* const* d_in, const int* in_sizes, int n_in,
                              void* d_out, int out_size, void* d_ws, size_t ws_size,
                              hipStream_t stream) {
    const float* f = (const float*)d_in[0];   // [8192,512] -> 32768 rows of 128
    const float* W = (const float*)d_in[1];   // [2048,128]

    float* loss = (float*)d_out;              // [8192]
    float* outv = (float*)d_out + BATCH;      // [8192*512]

    // workspace layout
    float*    wnorm = (float*)d_ws;                              // @0       (8 KB)
    _Float16* whf   = (_Float16*)((char*)d_ws + 8192);           // @8K    (512 KB)
    _Float16* wlf   = (_Float16*)((char*)d_ws + 532480);         // @520K  (512 KB)
    float*    bsp   = (float*)((char*)d_ws + 1056768);           // @1032K (256 KB)
    int*      bcp   = (int*)((char*)d_ws + 1318912);             // @1288K (256 KB)

    wconv_kernel<<<KCODES * 16 / 256, 256, 0, stream>>>(W, whf, wlf, wnorm);

    hipLaunchKernelGGL(vq_argmin, dim3(256), dim3(512), 135168, stream,
                       f, whf, wlf, wnorm, bsp, bcp);

    gather_kernel<<<BATCH, 256, 0, stream>>>(f, W, bsp, bcp, loss, outv);
}

// Round 7
// 87.681 us; speedup vs baseline: 5.4975x; 1.0145x over previous
//
#include <hip/hip_runtime.h>

#define D        128
#define KCODES   2048
#define NROWS    32768
#define BATCH    8192

typedef _Float16 f16x8  __attribute__((ext_vector_type(8)));
typedef float    f32x16 __attribute__((ext_vector_type(16)));

#define MFMA(a, b, c) __builtin_amdgcn_mfma_f32_32x32x16_f16((a), (b), (c), 0, 0, 0)
#define INV2048 4.8828125e-4f

static __device__ __forceinline__ f32x16 zero16() {
    f32x16 z;
#pragma unroll
    for (int i = 0; i < 16; ++i) z[i] = 0.0f;
    return z;
}

static __device__ __forceinline__ void gload16(const void* g, void* l) {
    __builtin_amdgcn_global_load_lds(
        (const __attribute__((address_space(1))) unsigned int*)g,
        (__attribute__((address_space(3))) unsigned int*)l, 16, 0, 0);
}

// ---------------------------------------------------------------------------
// Kernel A: W -> (wh, wl) fp16 hi/lo, fragment-linear layout + fp32 ||W||^2.
// Lane mapping (verified R2-R6): for 32-code block n0, kstep ks, lane l holds
// W[n0*32 + (l&31)][ks*16 + (l>>5)*8 + j], stored at f16x8 idx ((n0*8+ks)*64+l).
// ---------------------------------------------------------------------------
__global__ void wconv_kernel(const float* __restrict__ W,
                             _Float16* __restrict__ whf, _Float16* __restrict__ wlf,
                             float* __restrict__ wnorm) {
    int gid = blockIdx.x * 256 + threadIdx.x;    // 32768 = 2048 codes x 16 slots
    int n = gid >> 4, s = gid & 15;
    const float4* src = (const float4*)(W + (size_t)n * D + s * 8);
    float4 a = src[0], b = src[1];
    float va[8] = {a.x, a.y, a.z, a.w, b.x, b.y, b.z, b.w};
    f16x8 hi, lo;
    float ss = 0.0f;
#pragma unroll
    for (int j = 0; j < 8; ++j) {
        _Float16 h = (_Float16)va[j];
        hi[j] = h;
        lo[j] = (_Float16)((va[j] - (float)h) * 2048.0f);
        ss += va[j] * va[j];
    }
    int ks = s >> 1, sub = s & 1;
    size_t idx = ((size_t)((n >> 5) * 8 + ks) * 64 + sub * 32 + (n & 31));
    ((f16x8*)whf)[idx] = hi;
    ((f16x8*)wlf)[idx] = lo;
#pragma unroll
    for (int m = 1; m <= 8; m <<= 1) ss += __shfl_xor(ss, m);
    if (s == 0) wnorm[n] = ss;
}

// ---------------------------------------------------------------------------
// Kernel B: fused MFMA scores + argmin — 4 waves/SIMD TLP version.
// Grid 512 = 256 row-blocks (128 rows) x 2 code-halves, XCD-pinned halves.
// Block 512 thr = 8 waves = 4 wm (32 rows each) x 2 wn (32 codes/chunk).
// 16 chunks of 64 codes; 2 x 32KB LDS double-buffer + 4KB wnorm = 68KB
// -> 2 blocks/CU (cross-block phase diversity), ~120 VGPR -> 4 waves/SIMD.
// Per chunk per wave: 24 ds_read_b128 + 24 MFMA (single acc, 3-pass trick).
// ---------------------------------------------------------------------------
extern "C" __global__ void __launch_bounds__(512)
__attribute__((amdgpu_flat_work_group_size(512, 512)))
__attribute__((amdgpu_waves_per_eu(4, 4)))
vq_argmin(const float* __restrict__ f,
          const _Float16* __restrict__ whf, const _Float16* __restrict__ wlf,
          const float* __restrict__ wnorm,
          float* __restrict__ bsp, int* __restrict__ bcp) {
    extern __shared__ unsigned char lds[];   // [2][32768] dbuf | wnorm @65536

    const int b   = blockIdx.x;
    const int xcd = b & 7;
    const int cH  = xcd >> 2;                 // code half 0/1 -> XCD group
    const int rb  = (b >> 3) * 4 + (xcd & 3); // row block 0..255
    const int tid = threadIdx.x;
    const int w   = tid >> 6, l = tid & 63;
    const int wm  = w >> 1, wn = w & 1;
    const int l31 = l & 31, lh = l >> 5;
    const int rowsBase = rb * 128 + wm * 32;

    // ---- stage this half's wnorm (1024 floats = 4KB) into LDS ----
    if (tid < 256)
        gload16((const char*)wnorm + cH * 4096 + tid * 16, lds + 65536 + tid * 16);

    // ---- A-fragments: 32 rows of f in hi/lo fp16 (64 VGPR) ----
    f16x8 fh[8], fl[8];
#pragma unroll
    for (int ks = 0; ks < 8; ++ks) {
        const float4* p = (const float4*)(f + (size_t)(rowsBase + l31) * D
                                          + ks * 16 + lh * 8);
        float4 a = p[0], bb = p[1];
        float va[8] = {a.x, a.y, a.z, a.w, bb.x, bb.y, bb.z, bb.w};
        f16x8 hi, lo;
#pragma unroll
        for (int j = 0; j < 8; ++j) {
            _Float16 h = (_Float16)va[j];
            hi[j] = h;
            lo[j] = (_Float16)((va[j] - (float)h) * 2048.0f);
        }
        fh[ks] = hi;
        fl[ks] = lo;
    }

    __syncthreads();    // drains all vmcnt; wnorm LDS visible

    const char* ghB = (const char*)whf + (size_t)cH * 262144;
    const char* glB = (const char*)wlf + (size_t)cH * 262144;

#define STAGE(c) {                                                          \
        unsigned char* dB = lds + ((c) & 1) * 32768;                        \
        const char* gh = ghB + (size_t)(c) * 16384;                         \
        const char* gl = glB + (size_t)(c) * 16384;                         \
        gload16(gh + tid * 16,        dB + tid * 16);                       \
        gload16(gh + 8192 + tid * 16, dB + 8192 + tid * 16);                \
        gload16(gl + tid * 16,        dB + 16384 + tid * 16);               \
        gload16(gl + 8192 + tid * 16, dB + 24576 + tid * 16);               \
    }

    STAGE(0);                                 // 4 loads in flight

    float bestP[16];
#pragma unroll
    for (int e = 0; e < 16; ++e) bestP[e] = 3.4e38f;

    const float* wnL = (const float*)(lds + 65536);

    // chunk body: 24 ds_read_b128 + 24 MFMA, single acc, 3-pass trick
    auto body = [&](int t) {
        const unsigned char* wb = lds + (t & 1) * 32768 + wn * 8192;
        f32x16 a = zero16();
        __builtin_amdgcn_s_setprio(1);
#pragma unroll
        for (int ks = 0; ks < 8; ++ks) {
            f16x8 wh = *(const f16x8*)(wb + ks * 1024 + l * 16);
            f16x8 wl = *(const f16x8*)(wb + 16384 + ks * 1024 + l * 16);
            a = MFMA(fh[ks], wl, a);
            a = MFMA(fl[ks], wh, a);
        }
#pragma unroll
        for (int r = 0; r < 16; ++r) a[r] *= INV2048;
#pragma unroll
        for (int ks = 0; ks < 8; ++ks) {
            f16x8 wh = *(const f16x8*)(wb + ks * 1024 + l * 16);
            a = MFMA(fh[ks], wh, a);
        }
        __builtin_amdgcn_s_setprio(0);
        const float wv = wnL[t * 64 + wn * 32 + l31];
#pragma unroll
        for (int r = 0; r < 16; ++r) {
            float s = fmaf(-2.0f, a[r], wv);
            unsigned p = (__float_as_uint(s) & 0xFFFFFFF0u) | (unsigned)t;
            bestP[r] = fminf(bestP[r], __uint_as_float(p));
        }
    };

    // one vmcnt(0)+barrier per chunk; STAGE(t+1) overlaps body(t)
#pragma unroll 1
    for (int t = 0; t < 16; ++t) {
        asm volatile("s_waitcnt vmcnt(0)" ::: "memory");
        __builtin_amdgcn_s_barrier();         // all waves: chunk t landed,
        asm volatile("" ::: "memory");        // body(t-1) readers done
        if (t < 15) STAGE(t + 1);
        body(t);
    }
#undef STAGE

    // ---- reduction: butterfly over 32 code-cols, then across wn pair ----
    __syncthreads();
    float* redS = (float*)lds;                   // [128][2]
    int*   redC = (int*)(lds + 1024);            // [128][2]
#pragma unroll
    for (int e = 0; e < 16; ++e) {
        float s = bestP[e];
        int tE = (int)(__float_as_uint(s) & 15u);
        int c  = cH * 1024 + tE * 64 + wn * 32 + l31;
#pragma unroll
        for (int msk = 1; msk <= 16; msk <<= 1) {
            float s2 = __shfl_xor(s, msk);
            int   c2 = __shfl_xor(c, msk);
            if (s2 < s || (s2 == s && c2 < c)) { s = s2; c = c2; }
        }
        if (l31 == 0) {
            int row = wm * 32 + (e & 3) + 8 * (e >> 2) + 4 * lh;
            redS[row * 2 + wn] = s;
            redC[row * 2 + wn] = c;
        }
    }
    __syncthreads();
    if (tid < 128) {
        float s0 = redS[tid * 2], s1 = redS[tid * 2 + 1];
        int   c0 = redC[tid * 2], c1 = redC[tid * 2 + 1];
        bool take1 = (s1 < s0) || (s1 == s0 && c1 < c0);
        bsp[(size_t)cH * NROWS + rb * 128 + tid] = take1 ? s1 : s0;
        bcp[(size_t)cH * NROWS + rb * 128 + tid] = take1 ? c1 : c0;
    }
}

// ---------------------------------------------------------------------------
// Kernel C: merge the two code-half partials, gather W[j], write out + loss.
// ---------------------------------------------------------------------------
__global__ void gather_kernel(const float* __restrict__ f, const float* __restrict__ W,
                              const float* __restrict__ bsp, const int* __restrict__ bcp,
                              float* __restrict__ loss, float* __restrict__ outv) {
    int b  = blockIdx.x;
    int wv = threadIdx.x >> 6;
    int l  = threadIdx.x & 63;
    int n  = b * 4 + wv;
    float s0 = bsp[n], s1 = bsp[NROWS + n];
    int   c0 = bcp[n], c1 = bcp[NROWS + n];
    int j = (s1 < s0) ? c1 : c0;   // tie -> c0 (always < c1)
    float2 fv = reinterpret_cast<const float2*>(f + (size_t)n * D)[l];
    float2 wj = reinterpret_cast<const float2*>(W + (size_t)j * D)[l];
    reinterpret_cast<float2*>(outv + (size_t)n * D)[l] = wj;
    float dx = fv.x - wj.x, dy = fv.y - wj.y;
    float s = dx * dx + dy * dy;
#pragma unroll
    for (int off = 32; off; off >>= 1) s += __shfl_down(s, off);
    __shared__ float ls[4];
    if (l == 0) ls[wv] = s;
    __syncthreads();
    if (threadIdx.x == 0)
        loss[b] = 1.25f * 0.25f * (ls[0] + ls[1] + ls[2] + ls[3]);
}

// ---------------------------------------------------------------------------
extern "C" void kernel_launch(void* const* d_in, const int* in_sizes, int n_in,
                              void* d_out, int out_size, void* d_ws, size_t ws_size,
                              hipStream_t stream) {
    const float* f = (const float*)d_in[0];   // [8192,512] -> 32768 rows of 128
    const float* W = (const float*)d_in[1];   // [2048,128]

    float* loss = (float*)d_out;              // [8192]
    float* outv = (float*)d_out + BATCH;      // [8192*512]

    // workspace layout
    float*    wnorm = (float*)d_ws;                              // @0       (8 KB)
    _Float16* whf   = (_Float16*)((char*)d_ws + 8192);           // @8K    (512 KB)
    _Float16* wlf   = (_Float16*)((char*)d_ws + 532480);         // @520K  (512 KB)
    float*    bsp   = (float*)((char*)d_ws + 1056768);           // @1032K (256 KB)
    int*      bcp   = (int*)((char*)d_ws + 1318912);             // @1288K (256 KB)

    wconv_kernel<<<KCODES * 16 / 256, 256, 0, stream>>>(W, whf, wlf, wnorm);

    hipLaunchKernelGGL(vq_argmin, dim3(512), dim3(512), 69632, stream,
                       f, whf, wlf, wnorm, bsp, bcp);

    gather_kernel<<<BATCH, 256, 0, stream>>>(f, W, bsp, bcp, loss, outv);
}

// Round 8
// 86.904 us; speedup vs baseline: 5.5466x; 1.0089x over previous
//
#include <hip/hip_runtime.h>

#define D        128
#define KCODES   2048
#define NROWS    32768
#define BATCH    8192

typedef _Float16 f16x8  __attribute__((ext_vector_type(8)));
typedef float    f32x16 __attribute__((ext_vector_type(16)));

#define MFMA(a, b, c) __builtin_amdgcn_mfma_f32_32x32x16_f16((a), (b), (c), 0, 0, 0)
#define INV2048 4.8828125e-4f

static __device__ __forceinline__ f32x16 zero16() {
    f32x16 z;
#pragma unroll
    for (int i = 0; i < 16; ++i) z[i] = 0.0f;
    return z;
}

static __device__ __forceinline__ void gload16(const void* g, void* l) {
    __builtin_amdgcn_global_load_lds(
        (const __attribute__((address_space(1))) unsigned int*)g,
        (__attribute__((address_space(3))) unsigned int*)l, 16, 0, 0);
}

// ---------------------------------------------------------------------------
// Kernel A: W -> (wh, wl) fp16 hi/lo, fragment-linear layout + fp32 ||W||^2.
// Lane mapping (verified R2-R7): for 32-code block n0, kstep ks, lane l holds
// W[n0*32 + (l&31)][ks*16 + (l>>5)*8 + j], stored at f16x8 idx ((n0*8+ks)*64+l).
// ---------------------------------------------------------------------------
__global__ void wconv_kernel(const float* __restrict__ W,
                             _Float16* __restrict__ whf, _Float16* __restrict__ wlf,
                             float* __restrict__ wnorm) {
    int gid = blockIdx.x * 256 + threadIdx.x;    // 32768 = 2048 codes x 16 slots
    int n = gid >> 4, s = gid & 15;
    const float4* src = (const float4*)(W + (size_t)n * D + s * 8);
    float4 a = src[0], b = src[1];
    float va[8] = {a.x, a.y, a.z, a.w, b.x, b.y, b.z, b.w};
    f16x8 hi, lo;
    float ss = 0.0f;
#pragma unroll
    for (int j = 0; j < 8; ++j) {
        _Float16 h = (_Float16)va[j];
        hi[j] = h;
        lo[j] = (_Float16)((va[j] - (float)h) * 2048.0f);
        ss += va[j] * va[j];
    }
    int ks = s >> 1, sub = s & 1;
    size_t idx = ((size_t)((n >> 5) * 8 + ks) * 64 + sub * 32 + (n & 31));
    ((f16x8*)whf)[idx] = hi;
    ((f16x8*)wlf)[idx] = lo;
#pragma unroll
    for (int m = 1; m <= 8; m <<= 1) ss += __shfl_xor(ss, m);
    if (s == 0) wnorm[n] = ss;
}

// ---------------------------------------------------------------------------
// Kernel B: fused MFMA scores + argmin — 8-phase interleaved schedule (T3+T4).
// Grid 512 = 256 row-blocks (128 rows) x 2 code-halves, XCD-pinned halves.
// Block 512 thr = 8 waves = 4 wm (32 rows each) x 2 wn (32 codes/chunk).
// 16 chunks of 64 codes; 2 x 32KB LDS dbuf + 4KB wnorm = 68KB -> 2 blocks/CU.
// Per chunk: top {vmcnt(0); barrier}; then 8 phases, each
//   {ds_read wh,wl (ks) | every 2nd phase: 1 gload16 of chunk t+1
//    -> s_barrier -> lgkmcnt(0)+sched_barrier -> setprio(1) 3 MFMA setprio(0)}
// Two acc chains (cross accC, hi accH); merged in the per-chunk fold.
// ---------------------------------------------------------------------------
extern "C" __global__ void __launch_bounds__(512)
__attribute__((amdgpu_flat_work_group_size(512, 512)))
__attribute__((amdgpu_waves_per_eu(4, 4)))
vq_argmin(const float* __restrict__ f,
          const _Float16* __restrict__ whf, const _Float16* __restrict__ wlf,
          const float* __restrict__ wnorm,
          float* __restrict__ bsp, int* __restrict__ bcp) {
    extern __shared__ unsigned char lds[];   // [2][32768] dbuf | wnorm @65536

    const int b   = blockIdx.x;
    const int xcd = b & 7;
    const int cH  = xcd >> 2;                 // code half 0/1 -> XCD group
    const int rb  = (b >> 3) * 4 + (xcd & 3); // row block 0..255
    const int tid = threadIdx.x;
    const int w   = tid >> 6, l = tid & 63;
    const int wm  = w >> 1, wn = w & 1;
    const int l31 = l & 31, lh = l >> 5;
    const int rowsBase = rb * 128 + wm * 32;

    // ---- stage this half's wnorm (1024 floats = 4KB) into LDS ----
    if (tid < 256)
        gload16((const char*)wnorm + cH * 4096 + tid * 16, lds + 65536 + tid * 16);

    // ---- A-fragments: 32 rows of f in hi/lo fp16 (64 VGPR) ----
    f16x8 fh[8], fl[8];
#pragma unroll
    for (int ks = 0; ks < 8; ++ks) {
        const float4* p = (const float4*)(f + (size_t)(rowsBase + l31) * D
                                          + ks * 16 + lh * 8);
        float4 a = p[0], bb = p[1];
        float va[8] = {a.x, a.y, a.z, a.w, bb.x, bb.y, bb.z, bb.w};
        f16x8 hi, lo;
#pragma unroll
        for (int j = 0; j < 8; ++j) {
            _Float16 h = (_Float16)va[j];
            hi[j] = h;
            lo[j] = (_Float16)((va[j] - (float)h) * 2048.0f);
        }
        fh[ks] = hi;
        fl[ks] = lo;
    }

    __syncthreads();    // full drain: wnorm LDS visible, vmcnt==0 on all waves

    const char* ghB = (const char*)whf + (size_t)cH * 262144;
    const char* glB = (const char*)wlf + (size_t)cH * 262144;

    // quarter q of chunk c: q0/q1 = wh 8KB halves, q2/q3 = wl 8KB halves
#define STAGE_Q(c, q) {                                                     \
        unsigned char* dB = lds + ((c) & 1) * 32768;                        \
        if ((q) < 2) {                                                      \
            gload16(ghB + (size_t)(c) * 16384 + (q) * 8192 + tid * 16,      \
                    dB + (q) * 8192 + tid * 16);                            \
        } else {                                                            \
            gload16(glB + (size_t)(c) * 16384 + ((q) - 2) * 8192 + tid * 16,\
                    dB + 16384 + ((q) - 2) * 8192 + tid * 16);              \
        }                                                                   \
    }

    STAGE_Q(0, 0); STAGE_Q(0, 1); STAGE_Q(0, 2); STAGE_Q(0, 3);

    float bestP[16];
#pragma unroll
    for (int e = 0; e < 16; ++e) bestP[e] = 3.4e38f;

    const float* wnL = (const float*)(lds + 65536);

#pragma unroll 1
    for (int t = 0; t < 16; ++t) {
        // chunk top: my 4 gloads for chunk t done; barrier joins all waves'
        asm volatile("s_waitcnt vmcnt(0)" ::: "memory");
        __builtin_amdgcn_s_barrier();
        asm volatile("" ::: "memory");

        const unsigned char* wb = lds + (t & 1) * 32768 + wn * 8192;
        f32x16 accC = zero16(), accH = zero16();

        // ---- 8 phases: {2 ds_read | gload-issue -> barrier -> lgkm -> 3 MFMA}
#pragma unroll
        for (int ks = 0; ks < 8; ++ks) {
            f16x8 wh = *(const f16x8*)(wb + ks * 1024 + l * 16);
            f16x8 wl = *(const f16x8*)(wb + 16384 + ks * 1024 + l * 16);
            if ((ks & 1) == 0 && t < 15) STAGE_Q(t + 1, ks >> 1);
            __builtin_amdgcn_s_barrier();
            asm volatile("s_waitcnt lgkmcnt(0)" ::: "memory");
            __builtin_amdgcn_sched_barrier(0);
            __builtin_amdgcn_s_setprio(1);
            accC = MFMA(fh[ks], wl, accC);
            accH = MFMA(fh[ks], wh, accH);
            accC = MFMA(fl[ks], wh, accC);
            __builtin_amdgcn_s_setprio(0);
        }

        // ---- fold: s = wn - 2*(accH + accC/2048); pack t in low 4 bits ----
        const float wv = wnL[t * 64 + wn * 32 + l31];
#pragma unroll
        for (int r = 0; r < 16; ++r) {
            float sc = fmaf(INV2048, accC[r], accH[r]);
            float s  = fmaf(-2.0f, sc, wv);
            unsigned p = (__float_as_uint(s) & 0xFFFFFFF0u) | (unsigned)t;
            bestP[r] = fminf(bestP[r], __uint_as_float(p));
        }
    }
#undef STAGE_Q

    // ---- reduction: butterfly over 32 code-cols, then across wn pair ----
    __syncthreads();
    float* redS = (float*)lds;                   // [128][2]
    int*   redC = (int*)(lds + 1024);            // [128][2]
#pragma unroll
    for (int e = 0; e < 16; ++e) {
        float s = bestP[e];
        int tE = (int)(__float_as_uint(s) & 15u);
        int c  = cH * 1024 + tE * 64 + wn * 32 + l31;
#pragma unroll
        for (int msk = 1; msk <= 16; msk <<= 1) {
            float s2 = __shfl_xor(s, msk);
            int   c2 = __shfl_xor(c, msk);
            if (s2 < s || (s2 == s && c2 < c)) { s = s2; c = c2; }
        }
        if (l31 == 0) {
            int row = wm * 32 + (e & 3) + 8 * (e >> 2) + 4 * lh;
            redS[row * 2 + wn] = s;
            redC[row * 2 + wn] = c;
        }
    }
    __syncthreads();
    if (tid < 128) {
        float s0 = redS[tid * 2], s1 = redS[tid * 2 + 1];
        int   c0 = redC[tid * 2], c1 = redC[tid * 2 + 1];
        bool take1 = (s1 < s0) || (s1 == s0 && c1 < c0);
        bsp[(size_t)cH * NROWS + rb * 128 + tid] = take1 ? s1 : s0;
        bcp[(size_t)cH * NROWS + rb * 128 + tid] = take1 ? c1 : c0;
    }
}

// ---------------------------------------------------------------------------
// Kernel C: merge the two code-half partials, gather W[j], write out + loss.
// ---------------------------------------------------------------------------
__global__ void gather_kernel(const float* __restrict__ f, const float* __restrict__ W,
                              const float* __restrict__ bsp, const int* __restrict__ bcp,
                              float* __restrict__ loss, float* __restrict__ outv) {
    int b  = blockIdx.x;
    int wv = threadIdx.x >> 6;
    int l  = threadIdx.x & 63;
    int n  = b * 4 + wv;
    float s0 = bsp[n], s1 = bsp[NROWS + n];
    int   c0 = bcp[n], c1 = bcp[NROWS + n];
    int j = (s1 < s0) ? c1 : c0;   // tie -> c0 (always < c1)
    float2 fv = reinterpret_cast<const float2*>(f + (size_t)n * D)[l];
    float2 wj = reinterpret_cast<const float2*>(W + (size_t)j * D)[l];
    reinterpret_cast<float2*>(outv + (size_t)n * D)[l] = wj;
    float dx = fv.x - wj.x, dy = fv.y - wj.y;
    float s = dx * dx + dy * dy;
#pragma unroll
    for (int off = 32; off; off >>= 1) s += __shfl_down(s, off);
    __shared__ float ls[4];
    if (l == 0) ls[wv] = s;
    __syncthreads();
    if (threadIdx.x == 0)
        loss[b] = 1.25f * 0.25f * (ls[0] + ls[1] + ls[2] + ls[3]);
}

// ---------------------------------------------------------------------------
extern "C" void kernel_launch(void* const* d_in, const int* in_sizes, int n_in,
                              void* d_out, int out_size, void* d_ws, size_t ws_size,
                              hipStream_t stream) {
    const float* f = (const float*)d_in[0];   // [8192,512] -> 32768 rows of 128
    const float* W = (const float*)d_in[1];   // [2048,128]

    float* loss = (float*)d_out;              // [8192]
    float* outv = (float*)d_out + BATCH;      // [8192*512]

    // workspace layout
    float*    wnorm = (float*)d_ws;                              // @0       (8 KB)
    _Float16* whf   = (_Float16*)((char*)d_ws + 8192);           // @8K    (512 KB)
    _Float16* wlf   = (_Float16*)((char*)d_ws + 532480);         // @520K  (512 KB)
    float*    bsp   = (float*)((char*)d_ws + 1056768);           // @1032K (256 KB)
    int*      bcp   = (int*)((char*)d_ws + 1318912);             // @1288K (256 KB)

    wconv_kernel<<<KCODES * 16 / 256, 256, 0, stream>>>(W, whf, wlf, wnorm);

    hipLaunchKernelGGL(vq_argmin, dim3(512), dim3(512), 69632, stream,
                       f, whf, wlf, wnorm, bsp, bcp);

    gather_kernel<<<BATCH, 256, 0, stream>>>(f, W, bsp, bcp, loss, outv);
}